// Round 7
// baseline (120.717 us; speedup 1.0000x reference)
//
#include <hip/hip_runtime.h>
#include <math.h>

#define B 32
#define C 8
#define T 512
#define NSH 5
#define NCLS 10
#define NFEAT 160   // 4 groups * 5 * 8

// d_out layout (f32): out[320] | dists[5120] | probs[5120] | loss[1]
#define OUT_OFF    0
#define DIST_OFF   (B * NCLS)                 // 320
#define PROB_OFF   (DIST_OFF + B * NFEAT)     // 5440
#define LOSS_OFF   (PROB_OFF + B * NFEAT)     // 10560

// d_ws (f32) map:
//   [0..639]        div pair partials
//   [640..643]      |Wout| partials
//   [1024..134143]  normalized x, 256 rows x XSTRIDE(520) (8-float pad)
//   [140000..]      wT per group: layout [c][j][n] (5 consecutive n's per j)
//   [200000..]      per-slice (dist,dist^2) partials per group
#define XN_OFF   1024
#define XSTRIDE  520
#define WT0_OFF  140000   // 8*52*5  = 2080
#define WT1_OFF  142080   // 8*103*5 = 4120
#define WT2_OFF  146200   // 8*154*5 = 6160
#define WT3_OFF  152360   // 8*256*5 = 10240
#define P3_OFF   200000   // 256*5*5*2 = 12800
#define P2_OFF   212800   // 256*5*6*2 = 15360
#define P1_OFF   228160   // 256*5*7*2 = 17920
#define P0_OFF   246080   // 256*5*8*2 = 20480

// ---------------------------------------------------------------------------
// prep: normalize x rows (padded) + transpose w -> wT + loss partials
// ---------------------------------------------------------------------------
__global__ __launch_bounds__(256) void prep_kernel(
    const float* __restrict__ x,
    const float* __restrict__ w0, const float* __restrict__ w1,
    const float* __restrict__ w2, const float* __restrict__ w3,
    const float* __restrict__ Wout,
    float* __restrict__ wsf)
{
    const int blk  = blockIdx.x;
    const int tid  = threadIdx.x;
    const int wv   = __builtin_amdgcn_readfirstlane(tid >> 6);
    const int lane = tid & 63;

    if (blk < 64) {
        const int bc = blk * 4 + wv;
        const float* xr = x + bc * T;
        const float4 u0 = *(const float4*)(xr + lane * 4);
        const float4 u1 = *(const float4*)(xr + 256 + lane * 4);
        float s = u0.x + u0.y + u0.z + u0.w + u1.x + u1.y + u1.z + u1.w;
        #pragma unroll
        for (int off = 32; off; off >>= 1) s += __shfl_down(s, off);
        const float mu = __shfl(s, 0) * (1.0f / T);
        float sq = (u0.x-mu)*(u0.x-mu) + (u0.y-mu)*(u0.y-mu) + (u0.z-mu)*(u0.z-mu) + (u0.w-mu)*(u0.w-mu)
                 + (u1.x-mu)*(u1.x-mu) + (u1.y-mu)*(u1.y-mu) + (u1.z-mu)*(u1.z-mu) + (u1.w-mu)*(u1.w-mu);
        #pragma unroll
        for (int off = 32; off; off >>= 1) sq += __shfl_down(sq, off);
        const float var = __shfl(sq, 0) * (1.0f / (T - 1));
        const float ns  = 1.0f / (sqrtf(var) + 1e-8f);
        const float nbv = -mu * ns;
        float* xo = wsf + XN_OFF + bc * XSTRIDE;
        const float4 o0 = { fmaf(u0.x,ns,nbv), fmaf(u0.y,ns,nbv), fmaf(u0.z,ns,nbv), fmaf(u0.w,ns,nbv) };
        const float4 o1 = { fmaf(u1.x,ns,nbv), fmaf(u1.y,ns,nbv), fmaf(u1.z,ns,nbv), fmaf(u1.w,ns,nbv) };
        *(float4*)(xo + lane * 4)       = o0;
        *(float4*)(xo + 256 + lane * 4) = o1;
        if (lane < 2) *(float4*)(xo + T + lane * 4) = float4{0.f, 0.f, 0.f, 0.f};
    } else if (blk < 224) {
        // diversity pair partials: one ordered pair per wave
        const int task = (blk - 64) * 4 + wv;   // 0..639
        const int g  = task / 160;
        const int r  = task - g * 160;
        const int c  = r / 20;
        const int pr = r - c * 20;
        const int i  = pr >> 2;
        const int j0 = pr & 3;
        const int j  = j0 + (j0 >= i ? 1 : 0);
        const float* wptrs[4] = { w0, w1, w2, w3 };
        const int    Ls[4]    = { 52, 103, 154, 256 };
        const int L = Ls[g];
        const float* wi = wptrs[g] + (i * C + c) * L;
        const float* wj = wptrs[g] + (j * C + c) * L;
        float ss = 0.0f;
        for (int t2 = lane; t2 < L; t2 += 64) {
            const float df = wj[t2] - wi[t2] + 1e-6f;
            ss += df * df;
        }
        #pragma unroll
        for (int off = 32; off; off >>= 1) ss += __shfl_down(ss, off);
        if (lane == 0) wsf[task] = expf(-sqrtf(ss));
    } else if (blk == 224) {
        // |Wout| partials
        float rg = 0.0f;
        #pragma unroll
        for (int k2 = 0; k2 < 7; ++k2) {
            const int e = lane + k2 * 64;
            if (e < 400) rg += fabsf(Wout[wv * 400 + e]);
        }
        #pragma unroll
        for (int off = 32; off; off >>= 1) rg += __shfl_down(rg, off);
        if (lane == 0) wsf[640 + wv] = rg;
    } else {
        // w transpose: wT[c][j][n] = w[(n*8+c)*L + j]
        const int e = (blk - 225) * 256 + tid;   // 0..22783
        if (e < 2080) {
            constexpr int L = 52;
            const int c = e / (L*5), r2 = e % (L*5), j = r2 / 5, n = r2 % 5;
            wsf[WT0_OFF + e] = w0[(n*C + c)*L + j];
        } else if (e < 6200) {
            constexpr int L = 103;
            const int e2 = e - 2080;
            const int c = e2 / (L*5), r2 = e2 % (L*5), j = r2 / 5, n = r2 % 5;
            wsf[WT1_OFF + e2] = w1[(n*C + c)*L + j];
        } else if (e < 12360) {
            constexpr int L = 154;
            const int e2 = e - 6200;
            const int c = e2 / (L*5), r2 = e2 % (L*5), j = r2 / 5, n = r2 % 5;
            wsf[WT2_OFF + e2] = w2[(n*C + c)*L + j];
        } else if (e < 22600) {
            constexpr int L = 256;
            const int e2 = e - 12360;
            const int c = e2 / (L*5), r2 = e2 % (L*5), j = r2 / 5, n = r2 % 5;
            wsf[WT3_OFF + e2] = w3[(n*C + c)*L + j];
        }
    }
}

// ---------------------------------------------------------------------------
// shapelet: one wave per (bc, 64-m slice). Lane owns one window m; all 5 n's
// computed per x load. x lane-contiguous (4-5 lines/load); w via contiguous
// 40-float wave-uniform chunks from wT (separate restrict ptr -> s_load).
// ---------------------------------------------------------------------------
template<int L, int M, int S>
__device__ __forceinline__ void shapelet_task_p(
    const float* __restrict__ xn,
    const float* __restrict__ wt,    // group wT base [c][j][n]
    const float* __restrict__ pmg,   // group pcm base (c,m)
    float* __restrict__ part,        // group partial base
    int r)
{
    const int lane = threadIdx.x & 63;
    const int bc = r / S;
    const int ms = r - bc * S;
    const int c  = bc & 7;
    const int m  = ms * 64 + lane;
    const bool act = (m < M);
    const int mm = act ? m : 0;
    const float* xr = xn + bc * XSTRIDE + mm;
    const float* wp = wt + c * (L * 5);

    float a0 = 0, a1 = 0, a2 = 0, a3 = 0, a4 = 0;

    float xf[8];
    #pragma unroll
    for (int q = 0; q < 8; ++q) xf[q] = xr[q];

    constexpr int NB  = L / 8;
    constexpr int REM = L % 8;
    for (int it = 0; it < NB; ++it) {
        const int j = it * 8;
        float cw[40];                       // 40 consecutive, wave-uniform
        #pragma unroll
        for (int q = 0; q < 40; ++q) cw[q] = wp[j * 5 + q];
        float nxf[8];
        #pragma unroll
        for (int q = 0; q < 8; ++q) nxf[q] = xr[j + 8 + q];
        #pragma unroll
        for (int jj = 0; jj < 8; ++jj) {
            const float xv = xf[jj];
            a0 += fabsf(xv - cw[jj*5+0]);
            a1 += fabsf(xv - cw[jj*5+1]);
            a2 += fabsf(xv - cw[jj*5+2]);
            a3 += fabsf(xv - cw[jj*5+3]);
            a4 += fabsf(xv - cw[jj*5+4]);
        }
        #pragma unroll
        for (int q = 0; q < 8; ++q) xf[q] = nxf[q];
    }
    if constexpr (REM > 0) {
        constexpr int j = NB * 8;
        float cw[REM * 5];
        #pragma unroll
        for (int q = 0; q < REM * 5; ++q) cw[q] = wp[j * 5 + q];
        #pragma unroll
        for (int jj = 0; jj < REM; ++jj) {
            const float xv = xf[jj];
            a0 += fabsf(xv - cw[jj*5+0]);
            a1 += fabsf(xv - cw[jj*5+1]);
            a2 += fabsf(xv - cw[jj*5+2]);
            a3 += fabsf(xv - cw[jj*5+3]);
            a4 += fabsf(xv - cw[jj*5+4]);
        }
    }

    const float pmv = pmg[c * M + mm];
    constexpr float invL = 1.0f / (float)L;
    const float scale = invL * pmv;

    float dv[5], d2[5];
    dv[0] = act ? a0 * scale : INFINITY;
    dv[1] = act ? a1 * scale : INFINITY;
    dv[2] = act ? a2 * scale : INFINITY;
    dv[3] = act ? a3 * scale : INFINITY;
    dv[4] = act ? a4 * scale : INFINITY;
    #pragma unroll
    for (int n = 0; n < 5; ++n) d2[n] = act ? dv[n] * dv[n] : INFINITY;

    #pragma unroll
    for (int off = 32; off; off >>= 1) {
        #pragma unroll
        for (int n = 0; n < 5; ++n) {
            dv[n] = fminf(dv[n], __shfl_down(dv[n], off));
            d2[n] = fminf(d2[n], __shfl_down(d2[n], off));
        }
    }
    if (lane == 0) {
        #pragma unroll
        for (int n = 0; n < 5; ++n) {
            float* p = part + ((bc * 5 + n) * S + ms) * 2;
            p[0] = dv[n];
            p[1] = d2[n];
        }
    }
}

__global__ __launch_bounds__(256) void shapelet_kernel(
    const float* __restrict__ p0, const float* __restrict__ p1,
    const float* __restrict__ p2, const float* __restrict__ p3,
    float* __restrict__ wsf)
{
    const int wv = __builtin_amdgcn_readfirstlane(threadIdx.x >> 6);
    const int wt = blockIdx.x * 4 + wv;
    const float* xn = wsf + XN_OFF;

    if (wt < 1280)
        shapelet_task_p<256, 257, 5>(xn, wsf + WT3_OFF, p3, wsf + P3_OFF, wt);
    else if (wt < 2816)
        shapelet_task_p<154, 359, 6>(xn, wsf + WT2_OFF, p2, wsf + P2_OFF, wt - 1280);
    else if (wt < 4608)
        shapelet_task_p<103, 410, 7>(xn, wsf + WT1_OFF, p1, wsf + P1_OFF, wt - 2816);
    else
        shapelet_task_p< 52, 461, 8>(xn, wsf + WT0_OFF, p0, wsf + P0_OFF, wt - 4608);
}

// ---------------------------------------------------------------------------
// head2: block b (<32): slice-partial min reduce -> dists/probs + GEMV.
//        block 32: loss finalize.
// ---------------------------------------------------------------------------
__global__ __launch_bounds__(256) void head2_kernel(
    const float* __restrict__ Wout,
    const float* __restrict__ wsf,
    float* __restrict__ out)
{
    const int blk = blockIdx.x;
    const int tid = threadIdx.x;

    if (blk < B) {
        const int b = blk;
        __shared__ float pl[NFEAT];
        if (tid < NFEAT) {
            const int col = tid;              // col = 40*g + n*8 + c
            const int g   = col / 40;
            const int rem = col - g * 40;
            const int n   = rem >> 3;
            const int c   = rem & 7;
            const int bc  = b * C + c;
            int S, pbase;
            switch (g) {
                case 0:  S = 8; pbase = P0_OFF; break;
                case 1:  S = 7; pbase = P1_OFF; break;
                case 2:  S = 6; pbase = P2_OFF; break;
                default: S = 5; pbase = P3_OFF; break;
            }
            const float* p = wsf + pbase + ((bc * 5 + n) * S) * 2;
            float mnd = INFINITY, mn2 = INFINITY;
            for (int msi = 0; msi < S; ++msi) {
                mnd = fminf(mnd, p[msi * 2]);
                mn2 = fminf(mn2, p[msi * 2 + 1]);
            }
            out[DIST_OFF + b * NFEAT + col] = mnd;
            const float pb = expf(-mn2);
            out[PROB_OFF + b * NFEAT + col] = pb;
            pl[col] = pb;
        }
        __syncthreads();
        if (tid < NFEAT) {
            const int k = tid >> 4, seg = tid & 15;
            const float* wr = Wout + k * NFEAT + seg * 10;
            const float* pp = pl + seg * 10;
            float acc = 0.0f;
            #pragma unroll
            for (int q = 0; q < 10; ++q) acc += pp[q] * wr[q];
            #pragma unroll
            for (int off = 8; off; off >>= 1) acc += __shfl_down(acc, off, 16);
            if (seg == 0) out[OUT_OFF + b * NCLS + k] = acc;
        }
    } else if (tid < 64) {
        const int lane = tid;
        float dv = 0.0f, rg = 0.0f;
        #pragma unroll
        for (int r = 0; r < 10; ++r) dv += wsf[lane + r * 64];
        if (lane < 4) rg = wsf[640 + lane];
        #pragma unroll
        for (int off = 32; off; off >>= 1) {
            dv += __shfl_down(dv, off);
            rg += __shfl_down(rg, off);
        }
        if (lane == 0)
            out[LOSS_OFF] = 0.1f * (rg * (1.0f / 1600.0f)) + 0.1f * (dv * (1.0f / 200.0f));
    }
}

extern "C" void kernel_launch(void* const* d_in, const int* in_sizes, int n_in,
                              void* d_out, int out_size, void* d_ws, size_t ws_size,
                              hipStream_t stream) {
    // setup_inputs() dict order: x, w0, pcm0, w1, pcm1, w2, pcm2, w3, pcm3, W_out
    const float* x    = (const float*)d_in[0];
    const float* w0   = (const float*)d_in[1];
    const float* pcm0 = (const float*)d_in[2];
    const float* w1   = (const float*)d_in[3];
    const float* pcm1 = (const float*)d_in[4];
    const float* w2   = (const float*)d_in[5];
    const float* pcm2 = (const float*)d_in[6];
    const float* w3   = (const float*)d_in[7];
    const float* pcm3 = (const float*)d_in[8];
    const float* Wout = (const float*)d_in[9];
    float* out = (float*)d_out;
    float* wsf = (float*)d_ws;

    prep_kernel<<<314, 256, 0, stream>>>(x, w0, w1, w2, w3, Wout, wsf);
    shapelet_kernel<<<1664, 256, 0, stream>>>(pcm0, pcm1, pcm2, pcm3, wsf);
    head2_kernel<<<B + 1, 256, 0, stream>>>(Wout, wsf, out);
}

// Round 8
// 99.677 us; speedup vs baseline: 1.2111x; 1.2111x over previous
//
#include <hip/hip_runtime.h>
#include <math.h>

#define B 32
#define C 8
#define T 512
#define NSH 5
#define NCLS 10
#define NFEAT 160   // 4 groups * 5 * 8

// d_out layout (f32): out[320] | dists[5120] | probs[5120] | loss[1]
#define OUT_OFF    0
#define DIST_OFF   (B * NCLS)                 // 320
#define PROB_OFF   (DIST_OFF + B * NFEAT)     // 5440
#define LOSS_OFF   (PROB_OFF + B * NFEAT)     // 10560

// d_ws (f32) map:
//   [0..639]        div pair partials
//   [640..643]      |Wout| partials
//   [1024..134143]  normalized x, 256 rows x XSTRIDE(520) (8-float pad)
//   [200000..]      per-slice (dist,dist^2) partials per group
#define XN_OFF   1024
#define XSTRIDE  520
#define P3_OFF   200000   // 256*5*5*2 = 12800
#define P2_OFF   212800   // 256*5*6*2 = 15360
#define P1_OFF   228160   // 256*5*7*2 = 17920
#define P0_OFF   246080   // 256*5*8*2 = 20480

// ---------------------------------------------------------------------------
// prep: normalize x rows (padded) + loss partials
// ---------------------------------------------------------------------------
__global__ __launch_bounds__(256) void prep_kernel(
    const float* __restrict__ x,
    const float* __restrict__ w0, const float* __restrict__ w1,
    const float* __restrict__ w2, const float* __restrict__ w3,
    const float* __restrict__ Wout,
    float* __restrict__ wsf)
{
    const int blk  = blockIdx.x;
    const int tid  = threadIdx.x;
    const int wv   = __builtin_amdgcn_readfirstlane(tid >> 6);
    const int lane = tid & 63;

    if (blk < 64) {
        const int bc = blk * 4 + wv;
        const float* xr = x + bc * T;
        const float4 u0 = *(const float4*)(xr + lane * 4);
        const float4 u1 = *(const float4*)(xr + 256 + lane * 4);
        float s = u0.x + u0.y + u0.z + u0.w + u1.x + u1.y + u1.z + u1.w;
        #pragma unroll
        for (int off = 32; off; off >>= 1) s += __shfl_down(s, off);
        const float mu = __shfl(s, 0) * (1.0f / T);
        float sq = (u0.x-mu)*(u0.x-mu) + (u0.y-mu)*(u0.y-mu) + (u0.z-mu)*(u0.z-mu) + (u0.w-mu)*(u0.w-mu)
                 + (u1.x-mu)*(u1.x-mu) + (u1.y-mu)*(u1.y-mu) + (u1.z-mu)*(u1.z-mu) + (u1.w-mu)*(u1.w-mu);
        #pragma unroll
        for (int off = 32; off; off >>= 1) sq += __shfl_down(sq, off);
        const float var = __shfl(sq, 0) * (1.0f / (T - 1));
        const float ns  = 1.0f / (sqrtf(var) + 1e-8f);
        const float nbv = -mu * ns;
        float* xo = wsf + XN_OFF + bc * XSTRIDE;
        const float4 o0 = { fmaf(u0.x,ns,nbv), fmaf(u0.y,ns,nbv), fmaf(u0.z,ns,nbv), fmaf(u0.w,ns,nbv) };
        const float4 o1 = { fmaf(u1.x,ns,nbv), fmaf(u1.y,ns,nbv), fmaf(u1.z,ns,nbv), fmaf(u1.w,ns,nbv) };
        *(float4*)(xo + lane * 4)       = o0;
        *(float4*)(xo + 256 + lane * 4) = o1;
        if (lane < 2) *(float4*)(xo + T + lane * 4) = float4{0.f, 0.f, 0.f, 0.f};
    } else if (blk < 224) {
        // diversity pair partials: one ordered pair per wave
        const int task = (blk - 64) * 4 + wv;   // 0..639
        const int g  = task / 160;
        const int r  = task - g * 160;
        const int c  = r / 20;
        const int pr = r - c * 20;
        const int i  = pr >> 2;
        const int j0 = pr & 3;
        const int j  = j0 + (j0 >= i ? 1 : 0);
        const float* wptrs[4] = { w0, w1, w2, w3 };
        const int    Ls[4]    = { 52, 103, 154, 256 };
        const int L = Ls[g];
        const float* wi = wptrs[g] + (i * C + c) * L;
        const float* wj = wptrs[g] + (j * C + c) * L;
        float ss = 0.0f;
        for (int t2 = lane; t2 < L; t2 += 64) {
            const float df = wj[t2] - wi[t2] + 1e-6f;
            ss += df * df;
        }
        #pragma unroll
        for (int off = 32; off; off >>= 1) ss += __shfl_down(ss, off);
        if (lane == 0) wsf[task] = expf(-sqrtf(ss));
    } else {
        // |Wout| partials
        float rg = 0.0f;
        #pragma unroll
        for (int k2 = 0; k2 < 7; ++k2) {
            const int e = lane + k2 * 64;
            if (e < 400) rg += fabsf(Wout[wv * 400 + e]);
        }
        #pragma unroll
        for (int off = 32; off; off >>= 1) rg += __shfl_down(rg, off);
        if (lane == 0) wsf[640 + wv] = rg;
    }
}

// ---------------------------------------------------------------------------
// shapelet: one wave per (bc, 64-m slice). Lane owns one window m; all 5 n's
// share each x value. x loads lane-contiguous (4-5 lines/load). w rows read
// from the ORIGINAL read-only global arrays (uniform + never stored-through
// -> scalar s_load pipe). Both x and w chunks double-buffered (A/B roles
// alternate per iteration; prefetch hides latency under 80 VALU).
// ---------------------------------------------------------------------------
template<int L, int M, int S>
__device__ __forceinline__ void shapelet_task(
    const float* __restrict__ xn,
    const float* __restrict__ wg,    // group w base (n,c,l)
    const float* __restrict__ pmg,   // group pcm base (c,m)
    float* __restrict__ part,        // group partial base
    int r)
{
    constexpr int CL = C * L;
    const int lane = threadIdx.x & 63;
    const int bc = r / S;
    const int ms = r - bc * S;
    const int c  = bc & 7;
    const int m  = ms * 64 + lane;
    const bool act = (m < M);
    const int mm = act ? m : 0;
    const float* xr = xn + bc * XSTRIDE + mm;
    const float* wr = wg + c * L;

    float acc[5] = {0, 0, 0, 0, 0};

    constexpr int NB  = L / 8;
    constexpr int REM = L % 8;

    float xfA[8], xfB[8];
    float cwA[5][8], cwB[5][8];

    #pragma unroll
    for (int q = 0; q < 8; ++q) xfA[q] = xr[q];
    #pragma unroll
    for (int n = 0; n < 5; ++n) {
        #pragma unroll
        for (int q = 0; q < 8; ++q) cwA[n][q] = wr[n * CL + q];
    }

#define STEP(CUR_X, CUR_W, NXT_X, NXT_W, IT)                                \
    {                                                                       \
        const int jn = ((IT) + 1 < NB) ? ((IT) + 1) * 8 : 0;                \
        _Pragma("unroll")                                                   \
        for (int q = 0; q < 8; ++q) NXT_X[q] = xr[(IT) * 8 + 8 + q];        \
        _Pragma("unroll")                                                   \
        for (int n = 0; n < 5; ++n) {                                       \
            _Pragma("unroll")                                               \
            for (int q = 0; q < 8; ++q) NXT_W[n][q] = wr[n * CL + jn + q];  \
        }                                                                   \
        _Pragma("unroll")                                                   \
        for (int jj = 0; jj < 8; ++jj) {                                    \
            const float xv = CUR_X[jj];                                     \
            _Pragma("unroll")                                               \
            for (int n = 0; n < 5; ++n)                                     \
                acc[n] += fabsf(xv - CUR_W[n][jj]);                         \
        }                                                                   \
    }

    int it = 0;
    for (; it + 2 <= NB; it += 2) {
        STEP(xfA, cwA, xfB, cwB, it)
        STEP(xfB, cwB, xfA, cwA, it + 1)
    }
    if constexpr ((NB & 1) != 0) {
        STEP(xfA, cwA, xfB, cwB, NB - 1)
    }
#undef STEP

    if constexpr (REM > 0) {
        float xt[8];
        float wt5[5][8];
        #pragma unroll
        for (int q = 0; q < REM; ++q) xt[q] = xr[NB * 8 + q];
        #pragma unroll
        for (int n = 0; n < 5; ++n) {
            #pragma unroll
            for (int q = 0; q < REM; ++q) wt5[n][q] = wr[n * CL + NB * 8 + q];
        }
        #pragma unroll
        for (int jj = 0; jj < REM; ++jj) {
            const float xv = xt[jj];
            #pragma unroll
            for (int n = 0; n < 5; ++n) acc[n] += fabsf(xv - wt5[n][jj]);
        }
    }

    const float pmv = pmg[c * M + mm];
    constexpr float invL = 1.0f / (float)L;
    const float scale = invL * pmv;

    float dv[5], d2[5];
    #pragma unroll
    for (int n = 0; n < 5; ++n) {
        dv[n] = act ? acc[n] * scale : INFINITY;
        d2[n] = act ? dv[n] * dv[n] : INFINITY;
    }

    #pragma unroll
    for (int off = 32; off; off >>= 1) {
        #pragma unroll
        for (int n = 0; n < 5; ++n) {
            dv[n] = fminf(dv[n], __shfl_down(dv[n], off));
            d2[n] = fminf(d2[n], __shfl_down(d2[n], off));
        }
    }
    if (lane == 0) {
        #pragma unroll
        for (int n = 0; n < 5; ++n) {
            float* p = part + ((bc * 5 + n) * S + ms) * 2;
            p[0] = dv[n];
            p[1] = d2[n];
        }
    }
}

__global__ __launch_bounds__(256) void shapelet_kernel(
    const float* __restrict__ xn,
    const float* __restrict__ w0, const float* __restrict__ w1,
    const float* __restrict__ w2, const float* __restrict__ w3,
    const float* __restrict__ p0, const float* __restrict__ p1,
    const float* __restrict__ p2, const float* __restrict__ p3,
    float* __restrict__ part0, float* __restrict__ part1,
    float* __restrict__ part2, float* __restrict__ part3)
{
    const int wv = __builtin_amdgcn_readfirstlane(threadIdx.x >> 6);
    const int wt = blockIdx.x * 4 + wv;

    // longest group (g3) first for makespan
    if (wt < 1280)
        shapelet_task<256, 257, 5>(xn, w3, p3, part3, wt);
    else if (wt < 2816)
        shapelet_task<154, 359, 6>(xn, w2, p2, part2, wt - 1280);
    else if (wt < 4608)
        shapelet_task<103, 410, 7>(xn, w1, p1, part1, wt - 2816);
    else
        shapelet_task< 52, 461, 8>(xn, w0, p0, part0, wt - 4608);
}

// ---------------------------------------------------------------------------
// head2: block b (<32): slice-partial min reduce -> dists/probs + GEMV.
//        block 32: loss finalize.
// ---------------------------------------------------------------------------
__global__ __launch_bounds__(256) void head2_kernel(
    const float* __restrict__ Wout,
    const float* __restrict__ wsf,
    float* __restrict__ out)
{
    const int blk = blockIdx.x;
    const int tid = threadIdx.x;

    if (blk < B) {
        const int b = blk;
        __shared__ float pl[NFEAT];
        if (tid < NFEAT) {
            const int col = tid;              // col = 40*g + n*8 + c
            const int g   = col / 40;
            const int rem = col - g * 40;
            const int n   = rem >> 3;
            const int c   = rem & 7;
            const int bc  = b * C + c;
            int S, pbase;
            switch (g) {
                case 0:  S = 8; pbase = P0_OFF; break;
                case 1:  S = 7; pbase = P1_OFF; break;
                case 2:  S = 6; pbase = P2_OFF; break;
                default: S = 5; pbase = P3_OFF; break;
            }
            const float* p = wsf + pbase + ((bc * 5 + n) * S) * 2;
            float mnd = INFINITY, mn2 = INFINITY;
            for (int msi = 0; msi < S; ++msi) {
                mnd = fminf(mnd, p[msi * 2]);
                mn2 = fminf(mn2, p[msi * 2 + 1]);
            }
            out[DIST_OFF + b * NFEAT + col] = mnd;
            const float pb = expf(-mn2);
            out[PROB_OFF + b * NFEAT + col] = pb;
            pl[col] = pb;
        }
        __syncthreads();
        if (tid < NFEAT) {
            const int k = tid >> 4, seg = tid & 15;
            const float* wr = Wout + k * NFEAT + seg * 10;
            const float* pp = pl + seg * 10;
            float acc = 0.0f;
            #pragma unroll
            for (int q = 0; q < 10; ++q) acc += pp[q] * wr[q];
            #pragma unroll
            for (int off = 8; off; off >>= 1) acc += __shfl_down(acc, off, 16);
            if (seg == 0) out[OUT_OFF + b * NCLS + k] = acc;
        }
    } else if (tid < 64) {
        const int lane = tid;
        float dv = 0.0f, rg = 0.0f;
        #pragma unroll
        for (int r = 0; r < 10; ++r) dv += wsf[lane + r * 64];
        if (lane < 4) rg = wsf[640 + lane];
        #pragma unroll
        for (int off = 32; off; off >>= 1) {
            dv += __shfl_down(dv, off);
            rg += __shfl_down(rg, off);
        }
        if (lane == 0)
            out[LOSS_OFF] = 0.1f * (rg * (1.0f / 1600.0f)) + 0.1f * (dv * (1.0f / 200.0f));
    }
}

extern "C" void kernel_launch(void* const* d_in, const int* in_sizes, int n_in,
                              void* d_out, int out_size, void* d_ws, size_t ws_size,
                              hipStream_t stream) {
    // setup_inputs() dict order: x, w0, pcm0, w1, pcm1, w2, pcm2, w3, pcm3, W_out
    const float* x    = (const float*)d_in[0];
    const float* w0   = (const float*)d_in[1];
    const float* pcm0 = (const float*)d_in[2];
    const float* w1   = (const float*)d_in[3];
    const float* pcm1 = (const float*)d_in[4];
    const float* w2   = (const float*)d_in[5];
    const float* pcm2 = (const float*)d_in[6];
    const float* w3   = (const float*)d_in[7];
    const float* pcm3 = (const float*)d_in[8];
    const float* Wout = (const float*)d_in[9];
    float* out = (float*)d_out;
    float* wsf = (float*)d_ws;

    prep_kernel<<<225, 256, 0, stream>>>(x, w0, w1, w2, w3, Wout, wsf);
    shapelet_kernel<<<1664, 256, 0, stream>>>(
        wsf + XN_OFF, w0, w1, w2, w3, pcm0, pcm1, pcm2, pcm3,
        wsf + P0_OFF, wsf + P1_OFF, wsf + P2_OFF, wsf + P3_OFF);
    head2_kernel<<<B + 1, 256, 0, stream>>>(Wout, wsf, out);
}

// Round 10
// 99.134 us; speedup vs baseline: 1.2177x; 1.0055x over previous
//
#include <hip/hip_runtime.h>
#include <math.h>

#define B 32
#define C 8
#define T 512
#define NSH 5
#define NCLS 10
#define NFEAT 160   // 4 groups * 5 * 8

typedef float v2f __attribute__((ext_vector_type(2)));

// d_out layout (f32): out[320] | dists[5120] | probs[5120] | loss[1]
#define OUT_OFF    0
#define DIST_OFF   (B * NCLS)                 // 320
#define PROB_OFF   (DIST_OFF + B * NFEAT)     // 5440
#define LOSS_OFF   (PROB_OFF + B * NFEAT)     // 10560

// d_ws (f32) map:
//   [0..639]        div pair partials
//   [640..643]      |Wout| partials
//   [1024..134143]  normalized x, 256 rows x XSTRIDE(520) (8-float pad)
//   [200000..]      per-slice (dist,dist^2) partials per group
#define XN_OFF   1024
#define XSTRIDE  520
#define P3_OFF   200000   // 256*5*5*2 = 12800
#define P2_OFF   212800   // 256*5*6*2 = 15360
#define P1_OFF   228160   // 256*5*7*2 = 17920
#define P0_OFF   246080   // 256*5*8*2 = 20480

// ---------------------------------------------------------------------------
// prep: normalize x rows (padded) + loss partials
// ---------------------------------------------------------------------------
__global__ __launch_bounds__(256) void prep_kernel(
    const float* __restrict__ x,
    const float* __restrict__ w0, const float* __restrict__ w1,
    const float* __restrict__ w2, const float* __restrict__ w3,
    const float* __restrict__ Wout,
    float* __restrict__ wsf)
{
    const int blk  = blockIdx.x;
    const int tid  = threadIdx.x;
    const int wv   = __builtin_amdgcn_readfirstlane(tid >> 6);
    const int lane = tid & 63;

    if (blk < 64) {
        const int bc = blk * 4 + wv;
        const float* xr = x + bc * T;
        const float4 u0 = *(const float4*)(xr + lane * 4);
        const float4 u1 = *(const float4*)(xr + 256 + lane * 4);
        float s = u0.x + u0.y + u0.z + u0.w + u1.x + u1.y + u1.z + u1.w;
        #pragma unroll
        for (int off = 32; off; off >>= 1) s += __shfl_down(s, off);
        const float mu = __shfl(s, 0) * (1.0f / T);
        float sq = (u0.x-mu)*(u0.x-mu) + (u0.y-mu)*(u0.y-mu) + (u0.z-mu)*(u0.z-mu) + (u0.w-mu)*(u0.w-mu)
                 + (u1.x-mu)*(u1.x-mu) + (u1.y-mu)*(u1.y-mu) + (u1.z-mu)*(u1.z-mu) + (u1.w-mu)*(u1.w-mu);
        #pragma unroll
        for (int off = 32; off; off >>= 1) sq += __shfl_down(sq, off);
        const float var = __shfl(sq, 0) * (1.0f / (T - 1));
        const float ns  = 1.0f / (sqrtf(var) + 1e-8f);
        const float nbv = -mu * ns;
        float* xo = wsf + XN_OFF + bc * XSTRIDE;
        const float4 o0 = { fmaf(u0.x,ns,nbv), fmaf(u0.y,ns,nbv), fmaf(u0.z,ns,nbv), fmaf(u0.w,ns,nbv) };
        const float4 o1 = { fmaf(u1.x,ns,nbv), fmaf(u1.y,ns,nbv), fmaf(u1.z,ns,nbv), fmaf(u1.w,ns,nbv) };
        *(float4*)(xo + lane * 4)       = o0;
        *(float4*)(xo + 256 + lane * 4) = o1;
        if (lane < 2) *(float4*)(xo + T + lane * 4) = float4{0.f, 0.f, 0.f, 0.f};
    } else if (blk < 224) {
        // diversity pair partials: one ordered pair per wave
        const int task = (blk - 64) * 4 + wv;   // 0..639
        const int g  = task / 160;
        const int r  = task - g * 160;
        const int c  = r / 20;
        const int pr = r - c * 20;
        const int i  = pr >> 2;
        const int j0 = pr & 3;
        const int j  = j0 + (j0 >= i ? 1 : 0);
        const float* wptrs[4] = { w0, w1, w2, w3 };
        const int    Ls[4]    = { 52, 103, 154, 256 };
        const int L = Ls[g];
        const float* wi = wptrs[g] + (i * C + c) * L;
        const float* wj = wptrs[g] + (j * C + c) * L;
        float ss = 0.0f;
        for (int t2 = lane; t2 < L; t2 += 64) {
            const float df = wj[t2] - wi[t2] + 1e-6f;
            ss += df * df;
        }
        #pragma unroll
        for (int off = 32; off; off >>= 1) ss += __shfl_down(ss, off);
        if (lane == 0) wsf[task] = expf(-sqrtf(ss));
    } else {
        // |Wout| partials
        float rg = 0.0f;
        #pragma unroll
        for (int k2 = 0; k2 < 7; ++k2) {
            const int e = lane + k2 * 64;
            if (e < 400) rg += fabsf(Wout[wv * 400 + e]);
        }
        #pragma unroll
        for (int off = 32; off; off >>= 1) rg += __shfl_down(rg, off);
        if (lane == 0) wsf[640 + wv] = rg;
    }
}

// ---------------------------------------------------------------------------
// shapelet: one wave per (bc, 64-m slice). Lane owns one window m; all 5 n's
// share each x value. x loads lane-contiguous; w rows from read-only global
// args (uniform -> s_load, scalar pipe). x triple-buffered (2 blocks ahead),
// w double-buffered (1 ahead). Inner accumulate in packed f32 pairs:
// d = x2 - w2; acc2 += max(d, -d)  -> v_pk_add_f32 / v_pk_max_f32.
// ---------------------------------------------------------------------------
template<int L, int M, int S>
__device__ __forceinline__ void shapelet_task(
    const float* __restrict__ xn,
    const float* __restrict__ wg,    // group w base (n,c,l)
    const float* __restrict__ pmg,   // group pcm base (c,m)
    float* __restrict__ part,        // group partial base
    int r)
{
    constexpr int CL = C * L;
    const int lane = threadIdx.x & 63;
    const int bc = r / S;
    const int ms = r - bc * S;
    const int c  = bc & 7;
    const int m  = ms * 64 + lane;
    const bool act = (m < M);
    const int mm = act ? m : 0;
    const float* xr = xn + bc * XSTRIDE + mm;
    const float* wr = wg + c * L;

    v2f acc2[5];
    #pragma unroll
    for (int n = 0; n < 5; ++n) { acc2[n][0] = 0.0f; acc2[n][1] = 0.0f; }

    constexpr int NB  = L / 8;
    constexpr int REM = L % 8;

    float xfA[8], xfB[8], xfC[8];
    float cwA[5][8], cwB[5][8];

    // prologue: x blocks 0,1 ; w block 0
    #pragma unroll
    for (int q = 0; q < 8; ++q) xfA[q] = xr[q];
    #pragma unroll
    for (int q = 0; q < 8; ++q) xfB[q] = xr[8 + q];
    #pragma unroll
    for (int n = 0; n < 5; ++n) {
        #pragma unroll
        for (int q = 0; q < 8; ++q) cwA[n][q] = wr[n * CL + q];
    }

#define STEP(CX, NX, CW, NW, IT)                                            \
    {                                                                       \
        const int itc = (IT);                                               \
        const int jn = (itc + 1 < NB) ? (itc + 1) * 8 : 0;                  \
        const int jx = (itc + 2 < NB) ? (itc + 2) * 8 : 0;                  \
        _Pragma("unroll")                                                   \
        for (int n = 0; n < 5; ++n) {                                       \
            _Pragma("unroll")                                               \
            for (int q = 0; q < 8; ++q) NW[n][q] = wr[n * CL + jn + q];     \
        }                                                                   \
        _Pragma("unroll")                                                   \
        for (int q = 0; q < 8; ++q) NX[q] = xr[jx + q];                     \
        _Pragma("unroll")                                                   \
        for (int jj = 0; jj < 8; jj += 2) {                                 \
            v2f xv; xv[0] = CX[jj]; xv[1] = CX[jj + 1];                     \
            _Pragma("unroll")                                               \
            for (int n = 0; n < 5; ++n) {                                   \
                v2f wv; wv[0] = CW[n][jj]; wv[1] = CW[n][jj + 1];           \
                const v2f d = xv - wv;                                      \
                acc2[n] += __builtin_elementwise_max(d, -d);                \
            }                                                               \
        }                                                                   \
    }

    // main loop: unroll 6 (x rotation period 3 x w rotation period 2)
    #pragma unroll 1
    for (int itb = 0; itb + 6 <= NB; itb += 6) {
        // itb is always a multiple of 6 -> buffer roles are static
        STEP(xfA, xfC, cwA, cwB, itb + 0)
        STEP(xfB, xfA, cwB, cwA, itb + 1)
        STEP(xfC, xfB, cwA, cwB, itb + 2)
        STEP(xfA, xfC, cwB, cwA, itb + 3)
        STEP(xfB, xfA, cwA, cwB, itb + 4)
        STEP(xfC, xfB, cwB, cwA, itb + 5)
    }
    constexpr int TBASE = NB - (NB % 6);
    if constexpr (NB % 6 >= 1) STEP(xfA, xfC, cwA, cwB, TBASE + 0)
    if constexpr (NB % 6 >= 2) STEP(xfB, xfA, cwB, cwA, TBASE + 1)
    if constexpr (NB % 6 >= 3) STEP(xfC, xfB, cwA, cwB, TBASE + 2)
    if constexpr (NB % 6 >= 4) STEP(xfA, xfC, cwB, cwA, TBASE + 3)
    if constexpr (NB % 6 >= 5) STEP(xfB, xfA, cwA, cwB, TBASE + 4)
#undef STEP

    if constexpr (REM > 0) {        // scalar tail j = NB*8 .. L-1
        float xt[8];
        float wt5[5][8];
        #pragma unroll
        for (int q = 0; q < REM; ++q) xt[q] = xr[NB * 8 + q];
        #pragma unroll
        for (int n = 0; n < 5; ++n) {
            #pragma unroll
            for (int q = 0; q < REM; ++q) wt5[n][q] = wr[n * CL + NB * 8 + q];
        }
        #pragma unroll
        for (int jj = 0; jj < REM; ++jj) {
            const float xv = xt[jj];
            #pragma unroll
            for (int n = 0; n < 5; ++n) acc2[n][0] += fabsf(xv - wt5[n][jj]);
        }
    }

    const float pmv = pmg[c * M + mm];
    constexpr float invL = 1.0f / (float)L;
    const float scale = invL * pmv;

    float dv[5], d2[5];
    #pragma unroll
    for (int n = 0; n < 5; ++n) {
        const float a = acc2[n][0] + acc2[n][1];
        dv[n] = act ? a * scale : INFINITY;
        d2[n] = act ? dv[n] * dv[n] : INFINITY;
    }

    #pragma unroll
    for (int off = 32; off; off >>= 1) {
        #pragma unroll
        for (int n = 0; n < 5; ++n) {
            dv[n] = fminf(dv[n], __shfl_down(dv[n], off));
            d2[n] = fminf(d2[n], __shfl_down(d2[n], off));
        }
    }
    if (lane == 0) {
        #pragma unroll
        for (int n = 0; n < 5; ++n) {
            float* p = part + ((bc * 5 + n) * S + ms) * 2;
            p[0] = dv[n];
            p[1] = d2[n];
        }
    }
}

__global__ __launch_bounds__(256) void shapelet_kernel(
    const float* __restrict__ xn,
    const float* __restrict__ w0, const float* __restrict__ w1,
    const float* __restrict__ w2, const float* __restrict__ w3,
    const float* __restrict__ p0, const float* __restrict__ p1,
    const float* __restrict__ p2, const float* __restrict__ p3,
    float* __restrict__ part0, float* __restrict__ part1,
    float* __restrict__ part2, float* __restrict__ part3)
{
    const int wv = __builtin_amdgcn_readfirstlane(threadIdx.x >> 6);
    const int wt = blockIdx.x * 4 + wv;

    // longest group (g3) first for makespan
    if (wt < 1280)
        shapelet_task<256, 257, 5>(xn, w3, p3, part3, wt);
    else if (wt < 2816)
        shapelet_task<154, 359, 6>(xn, w2, p2, part2, wt - 1280);
    else if (wt < 4608)
        shapelet_task<103, 410, 7>(xn, w1, p1, part1, wt - 2816);
    else
        shapelet_task< 52, 461, 8>(xn, w0, p0, part0, wt - 4608);
}

// ---------------------------------------------------------------------------
// head2: block b (<32): slice-partial min reduce -> dists/probs + GEMV.
//        block 32: loss finalize.
// ---------------------------------------------------------------------------
__global__ __launch_bounds__(256) void head2_kernel(
    const float* __restrict__ Wout,
    const float* __restrict__ wsf,
    float* __restrict__ out)
{
    const int blk = blockIdx.x;
    const int tid = threadIdx.x;

    if (blk < B) {
        const int b = blk;
        __shared__ float pl[NFEAT];
        if (tid < NFEAT) {
            const int col = tid;              // col = 40*g + n*8 + c
            const int g   = col / 40;
            const int rem = col - g * 40;
            const int n   = rem >> 3;
            const int c   = rem & 7;
            const int bc  = b * C + c;
            int S, pbase;
            switch (g) {
                case 0:  S = 8; pbase = P0_OFF; break;
                case 1:  S = 7; pbase = P1_OFF; break;
                case 2:  S = 6; pbase = P2_OFF; break;
                default: S = 5; pbase = P3_OFF; break;
            }
            const float* p = wsf + pbase + ((bc * 5 + n) * S) * 2;
            float mnd = INFINITY, mn2 = INFINITY;
            for (int msi = 0; msi < S; ++msi) {
                mnd = fminf(mnd, p[msi * 2]);
                mn2 = fminf(mn2, p[msi * 2 + 1]);
            }
            out[DIST_OFF + b * NFEAT + col] = mnd;
            const float pb = expf(-mn2);
            out[PROB_OFF + b * NFEAT + col] = pb;
            pl[col] = pb;
        }
        __syncthreads();
        if (tid < NFEAT) {
            const int k = tid >> 4, seg = tid & 15;
            const float* wr = Wout + k * NFEAT + seg * 10;
            const float* pp = pl + seg * 10;
            float acc = 0.0f;
            #pragma unroll
            for (int q = 0; q < 10; ++q) acc += pp[q] * wr[q];
            #pragma unroll
            for (int off = 8; off; off >>= 1) acc += __shfl_down(acc, off, 16);
            if (seg == 0) out[OUT_OFF + b * NCLS + k] = acc;
        }
    } else if (tid < 64) {
        const int lane = tid;
        float dv = 0.0f, rg = 0.0f;
        #pragma unroll
        for (int r = 0; r < 10; ++r) dv += wsf[lane + r * 64];
        if (lane < 4) rg = wsf[640 + lane];
        #pragma unroll
        for (int off = 32; off; off >>= 1) {
            dv += __shfl_down(dv, off);
            rg += __shfl_down(rg, off);
        }
        if (lane == 0)
            out[LOSS_OFF] = 0.1f * (rg * (1.0f / 1600.0f)) + 0.1f * (dv * (1.0f / 200.0f));
    }
}

extern "C" void kernel_launch(void* const* d_in, const int* in_sizes, int n_in,
                              void* d_out, int out_size, void* d_ws, size_t ws_size,
                              hipStream_t stream) {
    // setup_inputs() dict order: x, w0, pcm0, w1, pcm1, w2, pcm2, w3, pcm3, W_out
    const float* x    = (const float*)d_in[0];
    const float* w0   = (const float*)d_in[1];
    const float* pcm0 = (const float*)d_in[2];
    const float* w1   = (const float*)d_in[3];
    const float* pcm1 = (const float*)d_in[4];
    const float* w2   = (const float*)d_in[5];
    const float* pcm2 = (const float*)d_in[6];
    const float* w3   = (const float*)d_in[7];
    const float* pcm3 = (const float*)d_in[8];
    const float* Wout = (const float*)d_in[9];
    float* out = (float*)d_out;
    float* wsf = (float*)d_ws;

    prep_kernel<<<225, 256, 0, stream>>>(x, w0, w1, w2, w3, Wout, wsf);
    shapelet_kernel<<<1664, 256, 0, stream>>>(
        wsf + XN_OFF, w0, w1, w2, w3, pcm0, pcm1, pcm2, pcm3,
        wsf + P0_OFF, wsf + P1_OFF, wsf + P2_OFF, wsf + P3_OFF);
    head2_kernel<<<B + 1, 256, 0, stream>>>(Wout, wsf, out);
}